// Round 2
// baseline (1497.660 us; speedup 1.0000x reference)
//
#include <hip/hip_runtime.h>
#include <hip/hip_bf16.h>
#include <math.h>

#define NN 50000
#define DD 128
#define LLAYERS 3
#define RR 16
#define EE 1600000

typedef unsigned int u32;

// ---------------- CSR build ----------------
__global__ __launch_bounds__(256) void k_hist(const int* __restrict__ rows, int* __restrict__ cnt){
  int e = blockIdx.x*256 + threadIdx.x;
  if (e < EE) atomicAdd(&cnt[rows[e]], 1);
}

__global__ __launch_bounds__(256) void k_scanA(const int* __restrict__ cnt, int* __restrict__ bsum){
  __shared__ int s[256];
  int i = blockIdx.x*256 + threadIdx.x;
  int v = (i < NN) ? cnt[i] : 0;
  s[threadIdx.x] = v; __syncthreads();
  for (int off=128; off>0; off>>=1){
    if (threadIdx.x < off) s[threadIdx.x] += s[threadIdx.x+off];
    __syncthreads();
  }
  if (threadIdx.x==0) bsum[blockIdx.x] = s[0];
}

__global__ __launch_bounds__(256) void k_scanB(int* bsum){
  __shared__ int s[256];
  int t = threadIdx.x;
  int v = bsum[t];
  s[t] = v; __syncthreads();
  for (int off=1; off<256; off<<=1){
    int x = (t>=off) ? s[t-off] : 0; __syncthreads();
    s[t] += x; __syncthreads();
  }
  bsum[t] = s[t] - v; // exclusive block offsets
}

__global__ __launch_bounds__(256) void k_scanC(const int* __restrict__ cnt, const int* __restrict__ bsum,
                        int* __restrict__ row_ptr, int* __restrict__ cursor){
  __shared__ int s[256];
  int t = threadIdx.x; int i = blockIdx.x*256 + t;
  int v = (i<NN)?cnt[i]:0;
  s[t]=v; __syncthreads();
  for (int off=1; off<256; off<<=1){
    int x=(t>=off)?s[t-off]:0; __syncthreads();
    s[t]+=x; __syncthreads();
  }
  if (i<NN){ int e = bsum[blockIdx.x] + s[t]-v; row_ptr[i]=e; cursor[i]=e; }
}

__global__ __launch_bounds__(256) void k_scatter(const int* __restrict__ rows, const int* __restrict__ cols,
                          const float* __restrict__ vals,
                          int* __restrict__ cursor, int* __restrict__ col_s, float* __restrict__ val_s){
  int e = blockIdx.x*256+threadIdx.x;
  if (e<EE){
    int r = rows[e];
    int p = atomicAdd(&cursor[r],1);
    col_s[p] = cols[e];
    val_s[p] = vals[e];
  }
}

// ---------------- init h and h_sum (both fp32) ----------------
__global__ __launch_bounds__(256) void k_init(const float4* __restrict__ nf, float4* __restrict__ h, float4* __restrict__ hs){
  int i = blockIdx.x*256 + threadIdx.x; // over N*D/4 = 1.6M float4
  float4 v = nf[i];
  h[i] = v;
  hs[i] = v;
}

// transpose gnn_W (L x D x D, row-major [l][j][k]) -> wT [l][k][j]
__global__ __launch_bounds__(256) void k_wT(const float* __restrict__ W, float* __restrict__ wT){
  int idx = blockIdx.x*256+threadIdx.x; // 49152
  int l = idx >> 14; int r = idx & 16383; int k = r >> 7; int j = r & 127;
  wT[(l<<14) + k*128 + j] = W[(l<<14) + j*128 + k];
}

// ---------------- SPMM: agg[row] = sum vals * h[col] ----------------
// one wave per row; half-waves (32 lanes x float4) process 2 edges in flight
__global__ __launch_bounds__(256) void k_spmm(const int* __restrict__ row_ptr, const int* __restrict__ cnt,
                       const int* __restrict__ col_s, const float* __restrict__ val_s,
                       const float* __restrict__ h, float* __restrict__ agg){
  int lane = threadIdx.x & 63;
  int wid = (blockIdx.x*blockDim.x + threadIdx.x) >> 6;
  int nw = (gridDim.x*blockDim.x) >> 6;
  int sub = lane >> 5, k = lane & 31;
  for (int row = wid; row < NN; row += nw){
    int base = row_ptr[row], n = cnt[row];
    float ax=0.f, ay=0.f, az=0.f, aw=0.f;
    for (int p = sub; p < n; p += 2){
      int col = col_s[base+p];
      float v = val_s[base+p];
      float4 hv = *(const float4*)&h[(size_t)col*128 + k*4];
      ax = fmaf(v, hv.x, ax); ay = fmaf(v, hv.y, ay);
      az = fmaf(v, hv.z, az); aw = fmaf(v, hv.w, aw);
    }
    ax += __shfl_xor(ax,32); ay += __shfl_xor(ay,32);
    az += __shfl_xor(az,32); aw += __shfl_xor(aw,32);
    if (sub==0){
      float4 o; o.x=ax; o.y=ay; o.z=az; o.w=aw;
      *(float4*)&agg[(size_t)row*128 + k*4] = o;
    }
  }
}

// ---------------- dense layer: h = elu(agg @ W^T + b); hs += h ----------------
// block = 256 threads, 16 rows; thread owns 2 cols x 4 rows
__global__ __launch_bounds__(256) void k_gemm(const float* __restrict__ agg, const float* __restrict__ wTl,
                       const float* __restrict__ bl,
                       float* __restrict__ h, float* __restrict__ hs){
  __shared__ float a_s[16*128];
  int t = threadIdx.x;
  int i0 = blockIdx.x * 16;
  const float4* src = (const float4*)(agg + (size_t)i0*128);
  float4* dst = (float4*)a_s;
  dst[t] = src[t]; dst[t+256] = src[t+256];
  __syncthreads();
  int jj = (t & 63)*2;
  int g = t >> 6;
  float b0 = bl[jj], b1 = bl[jj+1];
  float acc[4][2];
  #pragma unroll
  for (int r=0;r<4;r++){ acc[r][0]=b0; acc[r][1]=b1; }
  #pragma unroll 4
  for (int k=0;k<128;k++){
    float2 w = *(const float2*)&wTl[k*128 + jj];
    #pragma unroll
    for (int r=0;r<4;r++){
      float a = a_s[(g*4+r)*128 + k];
      acc[r][0] = fmaf(a, w.x, acc[r][0]);
      acc[r][1] = fmaf(a, w.y, acc[r][1]);
    }
  }
  #pragma unroll
  for (int r=0;r<4;r++){
    int row = i0 + g*4 + r;
    float e0 = acc[r][0] > 0.f ? acc[r][0] : expm1f(acc[r][0]);
    float e1 = acc[r][1] > 0.f ? acc[r][1] : expm1f(acc[r][1]);
    float2* hp = (float2*)&hs[(size_t)row*128 + jj];
    float2 hv = *hp; hv.x += e0; hv.y += e1; *hp = hv;
    float2 hn; hn.x = e0; hn.y = e1;
    *(float2*)&h[(size_t)row*128 + jj] = hn;
  }
}

// ---------------- z = column sums of hs ----------------
__global__ __launch_bounds__(256) void k_zsum(const float* __restrict__ hs, float* __restrict__ z){
  __shared__ float s[256];
  int t = threadIdx.x;
  int d = t & 127, half = t >> 7;
  float acc = 0.f;
  for (int i = blockIdx.x*2 + half; i < NN; i += gridDim.x*2)
    acc += hs[(size_t)i*128 + d];
  s[t] = acc; __syncthreads();
  if (t < 128) atomicAdd(&z[d], s[t] + s[t+128]);
}

__global__ __launch_bounds__(128) void k_hz(const float* __restrict__ z, const float* __restrict__ fc1W,
                     const float* __restrict__ fc1b, float* __restrict__ hz){
  __shared__ float zs[128];
  int j = threadIdx.x;
  zs[j] = z[j] * (1.0f / (4.0f * (float)NN));
  __syncthreads();
  float acc = fc1b[j];
  const float* wr = &fc1W[j*128];
  #pragma unroll 8
  for (int k=0;k<128;k++)
    acc = fmaf(zs[k], wr[k], acc);
  hz[j] = acc >= 0.f ? acc : 0.2f*acc;
}

__global__ __launch_bounds__(256) void k_wcol(const float* __restrict__ hz, const float* __restrict__ W,
                       const float* __restrict__ b, float* __restrict__ wcol){
  __shared__ float hzs[128];
  int t = threadIdx.x;
  if (t < 128) hzs[t] = hz[t];
  __syncthreads();
  int m = blockIdx.x*256 + t; // < 2048
  float acc = b[m];
  const float* wr = &W[(size_t)m*128];
  #pragma unroll 8
  for (int k=0;k<128;k++)
    acc = fmaf(hzs[k], wr[k], acc);
  wcol[m] = acc;
}

// ---------------- big GEMV: wrow[m] = fcrow_W[m,:] . hz + b[m] ----------------
// half-wave per row: 32 lanes x float4; 2 rows per wave iteration (1KB coalesced)
__global__ __launch_bounds__(256) void k_wrow(const float* __restrict__ hz, const float* __restrict__ W,
                       const float* __restrict__ b, float* __restrict__ wrow){
  int lane = threadIdx.x & 63;
  int sub = lane >> 5, k = lane & 31;
  float4 hk = *(const float4*)&hz[k*4];
  int wid = (blockIdx.x*blockDim.x + threadIdx.x) >> 6;
  int nw = (gridDim.x*blockDim.x) >> 6;
  const int NITER = NN*RR/2; // 400000
  for (int it = wid; it < NITER; it += nw){
    int row = it*2 + sub;
    float4 wv = *(const float4*)&W[(size_t)row*128 + k*4];
    float acc = wv.x*hk.x;
    acc = fmaf(wv.y, hk.y, acc);
    acc = fmaf(wv.z, hk.z, acc);
    acc = fmaf(wv.w, hk.w, acc);
    acc += __shfl_xor(acc,1); acc += __shfl_xor(acc,2);
    acc += __shfl_xor(acc,4); acc += __shfl_xor(acc,8);
    acc += __shfl_xor(acc,16);
    if (k==0) wrow[row] = acc + b[row];
  }
}

// ---------------- final: out = ini * (1 + W_row @ W_col) ----------------
__global__ __launch_bounds__(256) void k_final(const float* __restrict__ ini, const float* __restrict__ wrow,
                        const float* __restrict__ wcol, float* __restrict__ out){
  __shared__ float wc[16*128];
  int t = threadIdx.x;
  ((float4*)wc)[t] = ((const float4*)wcol)[t];
  ((float4*)wc)[t+256] = ((const float4*)wcol)[t+256];
  __syncthreads();
  int gid = blockIdx.x*256 + t; // N*32 = 1.6M
  int i = gid >> 5, k = gid & 31;
  float4 a; a.x=0.f; a.y=0.f; a.z=0.f; a.w=0.f;
  const float* wri = &wrow[(size_t)i*16];
  #pragma unroll
  for (int r=0;r<16;r++){
    float w = wri[r];
    const float4 c = *(const float4*)&wc[r*128 + k*4];
    a.x = fmaf(w, c.x, a.x); a.y = fmaf(w, c.y, a.y);
    a.z = fmaf(w, c.z, a.z); a.w = fmaf(w, c.w, a.w);
  }
  float4 e = *(const float4*)&ini[(size_t)i*128 + k*4];
  float4 o;
  o.x = e.x*(1.f+a.x); o.y = e.y*(1.f+a.y);
  o.z = e.z*(1.f+a.z); o.w = e.w*(1.f+a.w);
  *(float4*)&out[(size_t)i*128 + k*4] = o;
}

extern "C" void kernel_launch(void* const* d_in, const int* in_sizes, int n_in,
                              void* d_out, int out_size, void* d_ws, size_t ws_size,
                              hipStream_t stream) {
  const int* adj_rows = (const int*)d_in[0];
  const int* adj_cols = (const int*)d_in[1];
  const float* adj_vals = (const float*)d_in[2];
  const float* node_feats = (const float*)d_in[3];
  const float* gnn_W = (const float*)d_in[4];
  const float* gnn_b = (const float*)d_in[5];
  const float* fc1_W = (const float*)d_in[6];
  const float* fc1_b = (const float*)d_in[7];
  const float* fcrow_W = (const float*)d_in[8];
  const float* fcrow_b = (const float*)d_in[9];
  const float* fccol_W = (const float*)d_in[10];
  const float* fccol_b = (const float*)d_in[11];
  const float* ini = (const float*)d_in[12];
  float* out = (float*)d_out;

  char* w = (char*)d_ws;
  auto alloc = [&](size_t bytes)->void*{ void* p = (void*)w; w += (bytes + 255) & ~(size_t)255; return p; };
  float* h      = (float*)alloc((size_t)NN*DD*4);
  float* hs     = (float*)alloc((size_t)NN*DD*4);
  float* agg    = (float*)alloc((size_t)NN*DD*4);
  int*   col_s  = (int*)  alloc((size_t)EE*4);
  float* val_s  = (float*)alloc((size_t)EE*4);
  int*   cnt    = (int*)  alloc((size_t)NN*4);
  int*   row_ptr= (int*)  alloc((size_t)NN*4);
  int*   cursor = (int*)  alloc((size_t)NN*4);
  int*   bsum   = (int*)  alloc(256*4);
  float* wT     = (float*)alloc(3*128*128*4);
  float* zb     = (float*)alloc(128*4);
  float* hzb    = (float*)alloc(128*4);
  float* wcolb  = (float*)alloc(2048*4);
  float* wrowb  = (float*)alloc((size_t)NN*RR*4);

  hipMemsetAsync(cnt, 0, NN*4, stream);
  hipMemsetAsync(zb, 0, 128*4, stream);

  k_hist<<<EE/256, 256, 0, stream>>>(adj_rows, cnt);
  k_scanA<<<256, 256, 0, stream>>>(cnt, bsum);
  k_scanB<<<1, 256, 0, stream>>>(bsum);
  k_scanC<<<256, 256, 0, stream>>>(cnt, bsum, row_ptr, cursor);
  k_scatter<<<EE/256, 256, 0, stream>>>(adj_rows, adj_cols, adj_vals, cursor, col_s, val_s);
  k_init<<<NN*DD/4/256, 256, 0, stream>>>((const float4*)node_feats, (float4*)h, (float4*)hs);
  k_wT<<<3*128*128/256, 256, 0, stream>>>(gnn_W, wT);

  for (int l=0; l<LLAYERS; ++l){
    k_spmm<<<1024, 256, 0, stream>>>(row_ptr, cnt, col_s, val_s, h, agg);
    k_gemm<<<NN/16, 256, 0, stream>>>(agg, wT + l*16384, gnn_b + l*128, h, hs);
  }

  k_zsum<<<256, 256, 0, stream>>>(hs, zb);
  k_hz<<<1, 128, 0, stream>>>(zb, fc1_W, fc1_b, hzb);
  k_wcol<<<8, 256, 0, stream>>>(hzb, fccol_W, fccol_b, wcolb);
  k_wrow<<<2048, 256, 0, stream>>>(hzb, fcrow_W, fcrow_b, wrowb);
  k_final<<<NN*32/256, 256, 0, stream>>>(ini, wrowb, wcolb, out);
}

// Round 3
// 1283.005 us; speedup vs baseline: 1.1673x; 1.1673x over previous
//
#include <hip/hip_runtime.h>
#include <hip/hip_bf16.h>
#include <math.h>

#define NN 50000
#define DD 128
#define LLAYERS 3
#define RR 16
#define EE 1600000

typedef unsigned int u32;

__device__ __forceinline__ float bflo(u32 u){ union{u32 i;float f;}a; a.i=u<<16; return a.f; }
__device__ __forceinline__ float bfhi(u32 u){ union{u32 i;float f;}a; a.i=u&0xffff0000u; return a.f; }
__device__ __forceinline__ u32 pack_bf2(float x, float y){
  union{float f;u32 i;}a,b; a.f=x; b.f=y;
  u32 xr = (a.i + 0x7fffu + ((a.i>>16)&1u)) >> 16;
  u32 yr = (b.i + 0x7fffu + ((b.i>>16)&1u)) & 0xffff0000u;
  return (xr & 0xffffu) | yr;
}

// ---------------- CSR build ----------------
__global__ __launch_bounds__(256) void k_hist(const int* __restrict__ rows, int* __restrict__ cnt){
  int e = blockIdx.x*256 + threadIdx.x;
  if (e < EE) atomicAdd(&cnt[rows[e]], 1);
}

__global__ __launch_bounds__(256) void k_scanA(const int* __restrict__ cnt, int* __restrict__ bsum){
  __shared__ int s[256];
  int i = blockIdx.x*256 + threadIdx.x;
  int v = (i < NN) ? cnt[i] : 0;
  s[threadIdx.x] = v; __syncthreads();
  for (int off=128; off>0; off>>=1){
    if (threadIdx.x < off) s[threadIdx.x] += s[threadIdx.x+off];
    __syncthreads();
  }
  if (threadIdx.x==0) bsum[blockIdx.x] = s[0];
}

__global__ __launch_bounds__(256) void k_scanB(int* bsum){
  __shared__ int s[256];
  int t = threadIdx.x;
  int v = bsum[t];
  s[t] = v; __syncthreads();
  for (int off=1; off<256; off<<=1){
    int x = (t>=off) ? s[t-off] : 0; __syncthreads();
    s[t] += x; __syncthreads();
  }
  bsum[t] = s[t] - v; // exclusive block offsets
}

__global__ __launch_bounds__(256) void k_scanC(const int* __restrict__ cnt, const int* __restrict__ bsum,
                        int* __restrict__ row_ptr, int* __restrict__ cursor){
  __shared__ int s[256];
  int t = threadIdx.x; int i = blockIdx.x*256 + t;
  int v = (i<NN)?cnt[i]:0;
  s[t]=v; __syncthreads();
  for (int off=1; off<256; off<<=1){
    int x=(t>=off)?s[t-off]:0; __syncthreads();
    s[t]+=x; __syncthreads();
  }
  if (i<NN){ int e = bsum[blockIdx.x] + s[t]-v; row_ptr[i]=e; cursor[i]=e; }
}

__global__ __launch_bounds__(256) void k_scatter(const int* __restrict__ rows, const int* __restrict__ cols,
                          const float* __restrict__ vals,
                          int* __restrict__ cursor, int* __restrict__ col_s, float* __restrict__ val_s){
  int e = blockIdx.x*256+threadIdx.x;
  if (e<EE){
    int r = rows[e];
    int p = atomicAdd(&cursor[r],1);
    col_s[p] = cols[e];
    val_s[p] = vals[e];
  }
}

// ---------------- init: h -> bf16 packed, accumulate z column sums ----------------
__global__ __launch_bounds__(256) void k_init(const float4* __restrict__ nf, uint2* __restrict__ hbf,
                                              float* __restrict__ z){
  __shared__ float zp[128];
  int t = threadIdx.x;
  if (t < 128) zp[t] = 0.f;
  float a0=0.f,a1=0.f,a2=0.f,a3=0.f;
  // stride (gridDim*256 float4s) is a multiple of 32 float4 = 128 floats -> fixed columns per thread
  for (int i = blockIdx.x*256 + t; i < NN*DD/4; i += gridDim.x*256){
    float4 v = nf[i];
    uint2 p; p.x = pack_bf2(v.x, v.y); p.y = pack_bf2(v.z, v.w);
    hbf[i] = p;
    a0 += v.x; a1 += v.y; a2 += v.z; a3 += v.w;
  }
  __syncthreads();
  int c = (t*4) & 127;
  atomicAdd(&zp[c],a0); atomicAdd(&zp[c+1],a1); atomicAdd(&zp[c+2],a2); atomicAdd(&zp[c+3],a3);
  __syncthreads();
  if (t < 128) atomicAdd(&z[t], zp[t]);
}

// transpose gnn_W (L x D x D, row-major [l][j][k]) -> wT [l][k][j]
__global__ __launch_bounds__(256) void k_wT(const float* __restrict__ W, float* __restrict__ wT){
  int idx = blockIdx.x*256+threadIdx.x; // 49152
  int l = idx >> 14; int r = idx & 16383; int k = r >> 7; int j = r & 127;
  wT[(l<<14) + k*128 + j] = W[(l<<14) + j*128 + k];
}

// ---------------- SPMM: agg[row] = sum vals * h[col]  (h in bf16) ----------------
// one wave per row; quarter-waves (16 lanes x uint4 = 8 bf16) process 4 edges in flight
__global__ __launch_bounds__(256) void k_spmm(const int* __restrict__ row_ptr, const int* __restrict__ cnt,
                       const int* __restrict__ col_s, const float* __restrict__ val_s,
                       const u32* __restrict__ hbf, float* __restrict__ agg){
  int lane = threadIdx.x & 63;
  int wid = (blockIdx.x*blockDim.x + threadIdx.x) >> 6;
  int nw = (gridDim.x*blockDim.x) >> 6;
  int sub = lane >> 4, k = lane & 15;
  for (int row = wid; row < NN; row += nw){
    int base = row_ptr[row], n = cnt[row];
    float a0=0,a1=0,a2=0,a3=0,a4=0,a5=0,a6=0,a7=0;
    for (int p = sub; p < n; p += 4){
      int col = col_s[base+p];
      float v = val_s[base+p];
      uint4 hv = *(const uint4*)&hbf[(size_t)col*64 + k*4];   // features k*8..k*8+7
      a0 = fmaf(v, bflo(hv.x), a0); a1 = fmaf(v, bfhi(hv.x), a1);
      a2 = fmaf(v, bflo(hv.y), a2); a3 = fmaf(v, bfhi(hv.y), a3);
      a4 = fmaf(v, bflo(hv.z), a4); a5 = fmaf(v, bfhi(hv.z), a5);
      a6 = fmaf(v, bflo(hv.w), a6); a7 = fmaf(v, bfhi(hv.w), a7);
    }
    a0 += __shfl_xor(a0,16); a0 += __shfl_xor(a0,32);
    a1 += __shfl_xor(a1,16); a1 += __shfl_xor(a1,32);
    a2 += __shfl_xor(a2,16); a2 += __shfl_xor(a2,32);
    a3 += __shfl_xor(a3,16); a3 += __shfl_xor(a3,32);
    a4 += __shfl_xor(a4,16); a4 += __shfl_xor(a4,32);
    a5 += __shfl_xor(a5,16); a5 += __shfl_xor(a5,32);
    a6 += __shfl_xor(a6,16); a6 += __shfl_xor(a6,32);
    a7 += __shfl_xor(a7,16); a7 += __shfl_xor(a7,32);
    if (sub==0){
      float4 o0; o0.x=a0; o0.y=a1; o0.z=a2; o0.w=a3;
      float4 o1; o1.x=a4; o1.y=a5; o1.z=a6; o1.w=a7;
      *(float4*)&agg[(size_t)row*128 + k*8] = o0;
      *(float4*)&agg[(size_t)row*128 + k*8 + 4] = o1;
    }
  }
}

// ---------------- dense layer: h = elu(agg @ W^T + b) -> bf16; z += colsum(h) ----------------
// 16-row tiles, grid-stride; thread owns 2 cols x 4 rows
__global__ __launch_bounds__(256) void k_gemm(const float* __restrict__ agg, const float* __restrict__ wTl,
                       const float* __restrict__ bl,
                       u32* __restrict__ hbf, float* __restrict__ z){
  __shared__ float a_s[16*128];
  __shared__ float zp[128];
  int t = threadIdx.x;
  if (t < 128) zp[t] = 0.f;
  int jj = (t & 63)*2;
  int g = t >> 6;
  float b0 = bl[jj], b1 = bl[jj+1];
  float zc0 = 0.f, zc1 = 0.f;
  for (int tile = blockIdx.x; tile < NN/16; tile += gridDim.x){
    int i0 = tile * 16;
    __syncthreads();
    const float4* src = (const float4*)(agg + (size_t)i0*128);
    ((float4*)a_s)[t] = src[t]; ((float4*)a_s)[t+256] = src[t+256];
    __syncthreads();
    float acc[4][2];
    #pragma unroll
    for (int r=0;r<4;r++){ acc[r][0]=b0; acc[r][1]=b1; }
    #pragma unroll 4
    for (int k=0;k<128;k++){
      float2 w = *(const float2*)&wTl[k*128 + jj];
      #pragma unroll
      for (int r=0;r<4;r++){
        float a = a_s[(g*4+r)*128 + k];
        acc[r][0] = fmaf(a, w.x, acc[r][0]);
        acc[r][1] = fmaf(a, w.y, acc[r][1]);
      }
    }
    #pragma unroll
    for (int r=0;r<4;r++){
      int row = i0 + g*4 + r;
      float e0 = acc[r][0] > 0.f ? acc[r][0] : expm1f(acc[r][0]);
      float e1 = acc[r][1] > 0.f ? acc[r][1] : expm1f(acc[r][1]);
      zc0 += e0; zc1 += e1;
      hbf[(size_t)row*64 + (jj>>1)] = pack_bf2(e0, e1);
    }
  }
  atomicAdd(&zp[jj], zc0); atomicAdd(&zp[jj+1], zc1);
  __syncthreads();
  if (t < 128) atomicAdd(&z[t], zp[t]);
}

__global__ __launch_bounds__(128) void k_hz(const float* __restrict__ z, const float* __restrict__ fc1W,
                     const float* __restrict__ fc1b, float* __restrict__ hz){
  __shared__ float zs[128];
  int j = threadIdx.x;
  zs[j] = z[j] * (1.0f / (4.0f * (float)NN));
  __syncthreads();
  float acc = fc1b[j];
  const float* wr = &fc1W[j*128];
  #pragma unroll 8
  for (int k=0;k<128;k++)
    acc = fmaf(zs[k], wr[k], acc);
  hz[j] = acc >= 0.f ? acc : 0.2f*acc;
}

__global__ __launch_bounds__(256) void k_wcol(const float* __restrict__ hz, const float* __restrict__ W,
                       const float* __restrict__ b, float* __restrict__ wcol){
  __shared__ float hzs[128];
  int t = threadIdx.x;
  if (t < 128) hzs[t] = hz[t];
  __syncthreads();
  int m = blockIdx.x*256 + t; // < 2048
  float acc = b[m];
  const float* wr = &W[(size_t)m*128];
  #pragma unroll 8
  for (int k=0;k<128;k++)
    acc = fmaf(hzs[k], wr[k], acc);
  wcol[m] = acc;
}

// ---------------- big GEMV: wrow[m] = fcrow_W[m,:] . hz + b[m] ----------------
__global__ __launch_bounds__(256) void k_wrow(const float* __restrict__ hz, const float* __restrict__ W,
                       const float* __restrict__ b, float* __restrict__ wrow){
  int lane = threadIdx.x & 63;
  int sub = lane >> 5, k = lane & 31;
  float4 hk = *(const float4*)&hz[k*4];
  int wid = (blockIdx.x*blockDim.x + threadIdx.x) >> 6;
  int nw = (gridDim.x*blockDim.x) >> 6;
  const int NITER = NN*RR/2; // 400000
  for (int it = wid; it < NITER; it += nw){
    int row = it*2 + sub;
    float4 wv = *(const float4*)&W[(size_t)row*128 + k*4];
    float acc = wv.x*hk.x;
    acc = fmaf(wv.y, hk.y, acc);
    acc = fmaf(wv.z, hk.z, acc);
    acc = fmaf(wv.w, hk.w, acc);
    acc += __shfl_xor(acc,1); acc += __shfl_xor(acc,2);
    acc += __shfl_xor(acc,4); acc += __shfl_xor(acc,8);
    acc += __shfl_xor(acc,16);
    if (k==0) wrow[row] = acc + b[row];
  }
}

// ---------------- final: out = ini * (1 + W_row @ W_col) ----------------
__global__ __launch_bounds__(256) void k_final(const float* __restrict__ ini, const float* __restrict__ wrow,
                        const float* __restrict__ wcol, float* __restrict__ out){
  __shared__ float wc[16*128];
  int t = threadIdx.x;
  ((float4*)wc)[t] = ((const float4*)wcol)[t];
  ((float4*)wc)[t+256] = ((const float4*)wcol)[t+256];
  __syncthreads();
  int gid = blockIdx.x*256 + t; // N*32 = 1.6M
  int i = gid >> 5, k = gid & 31;
  float4 a; a.x=0.f; a.y=0.f; a.z=0.f; a.w=0.f;
  const float* wri = &wrow[(size_t)i*16];
  #pragma unroll
  for (int r=0;r<16;r++){
    float w = wri[r];
    const float4 c = *(const float4*)&wc[r*128 + k*4];
    a.x = fmaf(w, c.x, a.x); a.y = fmaf(w, c.y, a.y);
    a.z = fmaf(w, c.z, a.z); a.w = fmaf(w, c.w, a.w);
  }
  float4 e = *(const float4*)&ini[(size_t)i*128 + k*4];
  float4 o;
  o.x = e.x*(1.f+a.x); o.y = e.y*(1.f+a.y);
  o.z = e.z*(1.f+a.z); o.w = e.w*(1.f+a.w);
  *(float4*)&out[(size_t)i*128 + k*4] = o;
}

extern "C" void kernel_launch(void* const* d_in, const int* in_sizes, int n_in,
                              void* d_out, int out_size, void* d_ws, size_t ws_size,
                              hipStream_t stream) {
  const int* adj_rows = (const int*)d_in[0];
  const int* adj_cols = (const int*)d_in[1];
  const float* adj_vals = (const float*)d_in[2];
  const float* node_feats = (const float*)d_in[3];
  const float* gnn_W = (const float*)d_in[4];
  const float* gnn_b = (const float*)d_in[5];
  const float* fc1_W = (const float*)d_in[6];
  const float* fc1_b = (const float*)d_in[7];
  const float* fcrow_W = (const float*)d_in[8];
  const float* fcrow_b = (const float*)d_in[9];
  const float* fccol_W = (const float*)d_in[10];
  const float* fccol_b = (const float*)d_in[11];
  const float* ini = (const float*)d_in[12];
  float* out = (float*)d_out;

  char* w = (char*)d_ws;
  auto alloc = [&](size_t bytes)->void*{ void* p = (void*)w; w += (bytes + 255) & ~(size_t)255; return p; };
  u32*   hbf    = (u32*)  alloc((size_t)NN*DD*2);   // h as packed bf16
  float* agg    = (float*)alloc((size_t)NN*DD*4);
  int*   col_s  = (int*)  alloc((size_t)EE*4);
  float* val_s  = (float*)alloc((size_t)EE*4);
  int*   cnt    = (int*)  alloc((size_t)NN*4);
  int*   row_ptr= (int*)  alloc((size_t)NN*4);
  int*   cursor = (int*)  alloc((size_t)NN*4);
  int*   bsum   = (int*)  alloc(256*4);
  float* wT     = (float*)alloc(3*128*128*4);
  float* zb     = (float*)alloc(128*4);
  float* hzb    = (float*)alloc(128*4);
  float* wcolb  = (float*)alloc(2048*4);
  float* wrowb  = (float*)alloc((size_t)NN*RR*4);

  hipMemsetAsync(cnt, 0, NN*4, stream);
  hipMemsetAsync(zb, 0, 128*4, stream);

  k_hist<<<EE/256, 256, 0, stream>>>(adj_rows, cnt);
  k_scanA<<<256, 256, 0, stream>>>(cnt, bsum);
  k_scanB<<<1, 256, 0, stream>>>(bsum);
  k_scanC<<<256, 256, 0, stream>>>(cnt, bsum, row_ptr, cursor);
  k_scatter<<<EE/256, 256, 0, stream>>>(adj_rows, adj_cols, adj_vals, cursor, col_s, val_s);
  k_init<<<400, 256, 0, stream>>>((const float4*)node_feats, (uint2*)hbf, zb);
  k_wT<<<3*128*128/256, 256, 0, stream>>>(gnn_W, wT);

  for (int l=0; l<LLAYERS; ++l){
    k_spmm<<<1024, 256, 0, stream>>>(row_ptr, cnt, col_s, val_s, hbf, agg);
    k_gemm<<<625, 256, 0, stream>>>(agg, wT + l*16384, gnn_b + l*128, hbf, zb);
  }

  k_hz<<<1, 128, 0, stream>>>(zb, fc1_W, fc1_b, hzb);
  k_wcol<<<8, 256, 0, stream>>>(hzb, fccol_W, fccol_b, wcolb);
  k_wrow<<<2048, 256, 0, stream>>>(hzb, fcrow_W, fcrow_b, wrowb);
  k_final<<<NN*32/256, 256, 0, stream>>>(ini, wrowb, wcolb, out);
}